// Round 20
// baseline (144.514 us; speedup 1.0000x reference)
//
#include <hip/hip_runtime.h>
#include <hip/hip_bf16.h>

#define B_ 2048
#define D_ 17
#define H_ 8
#define HID_ 256
#define OUT_ 23
#define XROW 8721       /* 513*17 floats per batch */
#define SEQN 8704       /* 512*17 seq floats per batch */
#define LAST4 4465151   /* last valid float4 index of x (2048*8721/4 - 1) */

typedef unsigned int u32;
typedef const __attribute__((address_space(1))) u32* gp1_t;
typedef __attribute__((address_space(3))) u32* lp3_t;

__device__ __forceinline__ float bclane(float v, int l) {  // wave broadcast via readlane
  return __uint_as_float(__builtin_amdgcn_readlane(__float_as_uint(v), l));
}
__device__ __forceinline__ void gload_lds16(const float4* gsrc_lane, float* lds_wave_base) {
  __builtin_amdgcn_global_load_lds((gp1_t)(const void*)gsrc_lane,
                                   (lp3_t)(void*)lds_wave_base, 16, 0, 0);
}

// ---------------- Kernel 1: prep — transpose W2s + fold q into Wk ----------------
__global__ __launch_bounds__(256) void prep_kernel(
    const float* __restrict__ pW2, const float* __restrict__ vW2,
    const float* __restrict__ Wk, const float* __restrict__ bk,
    const float* __restrict__ q,
    float* __restrict__ pW2t, float* __restrict__ vW2t, float* __restrict__ qkc)
{
  const int bid = blockIdx.x;
  const int t = threadIdx.x;
  if (bid == 128) {
    if (t < H_ * D_) {
      const int h = t / D_, dd = t - h * D_;
      float s = 0.f;
      #pragma unroll
      for (int e = 0; e < D_; ++e) s = fmaf(Wk[h*289 + e*D_ + dd], q[h*D_ + e], s);
      qkc[h*18 + dd] = s;
    } else if (t < H_ * D_ + H_) {
      const int h = t - H_ * D_;
      float s = 0.f;
      #pragma unroll
      for (int e = 0; e < D_; ++e) s = fmaf(bk[h*D_ + e], q[h*D_ + e], s);
      qkc[h*18 + 17] = s;
    }
    return;
  }
  __shared__ float tile[32][33];
  const int m = bid >> 6, tid = bid & 63;
  const int ti = (tid >> 3) * 32, tk = (tid & 7) * 32;
  const float* src = m ? vW2 : pW2;
  float* dst = m ? vW2t : pW2t;
  const int tx = t & 31, ty = t >> 5;
  #pragma unroll
  for (int r = 0; r < 4; ++r) tile[ty + 8*r][tx] = src[(ti + ty + 8*r)*HID_ + tk + tx];
  __syncthreads();
  #pragma unroll
  for (int r = 0; r < 4; ++r) dst[(tk + ty + 8*r)*HID_ + ti + tx] = tile[tx][ty + 8*r];
}

// ---------------- Kernel 2: zero the producer-consumer flags (every launch) ----------------
__global__ __launch_bounds__(512) void zeroflags_kernel(int* __restrict__ flags) {
  const int i = blockIdx.x * 512 + threadIdx.x;
  if (i < B_) flags[i] = 0;
}

// ---------------- Kernel 3: single-grid producer/consumer attention + MLPs ----------------
// Blocks 0..2047: R15-proven attn for batch b -> comb[b] -> flag[b] (device-scope release).
// Blocks 2048..2559: mlp for batches mid*4..+3 after spin-acquiring the 4 flags.
// Capacity: 40.8KB LDS -> 3 blocks/CU -> 768 resident > 512 mlp blocks => no deadlock.
__global__ __launch_bounds__(256, 3) void fused_pc_kernel(
    const float* __restrict__ x, const float* __restrict__ qkc,
    const float* __restrict__ Wv, const float* __restrict__ bv,
    const float* __restrict__ Wo, const float* __restrict__ bo,
    const float* __restrict__ pW1, const float* __restrict__ pb1,
    const float* __restrict__ pW2t, const float* __restrict__ pb2,
    const float* __restrict__ pW3, const float* __restrict__ pb3,
    const float* __restrict__ vW1, const float* __restrict__ vb1,
    const float* __restrict__ vW2t, const float* __restrict__ vb2,
    const float* __restrict__ vW3, const float* __restrict__ vb3,
    float* __restrict__ comb, int* __restrict__ flags,
    float* __restrict__ out)
{
  __shared__ __align__(16) float smem[10200];   // attn: seq 9216 | part 576 | swn/agg/wp 408
  const int t = threadIdx.x;
  const int bid = blockIdx.x;

  if (bid < B_) {
    // ======================= ATTN role (R15-proven) =======================
    float* s_seq = smem;                    // [9216]
    float* s_part = smem + 9216;            // [4][8][18]
    float* s_swn = smem + 9792;             // [136]
    float* s_agg = smem + 9928;             // [136]
    float* s_wp  = smem + 10064;            // [136]

    const int w = t >> 6, lane = t & 63;
    const int hp = lane >> 4;
    const int rg = lane & 15;
    const int b = bid;
    const int seq0 = b * XROW + D_;
    const int s4 = seq0 >> 2;
    const int phase = seq0 & 3;
    const float4* __restrict__ x4 = (const float4*)x;

    const float pv = x[seq0 + lane * 136];  // probe first

    {
      float* dstb = s_seq + ((t & ~63) << 2);
      const int g0 = s4 + t;
      gload_lds16(x4 + g0,          dstb);
      gload_lds16(x4 + g0 + 256,    dstb + 1024);
      gload_lds16(x4 + g0 + 512,    dstb + 2048);
      gload_lds16(x4 + g0 + 768,    dstb + 3072);
      gload_lds16(x4 + g0 + 1024,   dstb + 4096);

      const unsigned long long live = __ballot(pv != 0.f) | 1ull;
      const int nr = 8 * (64 - __builtin_clzll(live));
      const int rounds = min(9, (nr * D_ + phase + 1023) >> 10);

      if (rounds > 5) gload_lds16(x4 + g0 + 1280, dstb + 5120);
      if (rounds > 6) gload_lds16(x4 + g0 + 1536, dstb + 6144);
      if (rounds > 7) gload_lds16(x4 + g0 + 1792, dstb + 7168);
      if (rounds > 8) gload_lds16(x4 + min(g0 + 2048, LAST4), dstb + 8192);
    }
    const unsigned long long live2 = __ballot(pv != 0.f) | 1ull;
    const int nrows = 8 * (64 - __builtin_clzll(live2));

    const float* q0 = qkc + (2*hp) * 18;
    float qk0[D_], qk1[D_];
    #pragma unroll
    for (int d = 0; d < D_; ++d) { qk0[d] = q0[d]; qk1[d] = q0[18 + d]; }
    const float ch0 = q0[17], ch1 = q0[35];

    __syncthreads();

    float den0 = 0.f, den1 = 0.f;
    float acc0[D_], acc1[D_];
    #pragma unroll
    for (int d = 0; d < D_; ++d) { acc0[d] = 0.f; acc1[d] = 0.f; }

    auto dorow = [&](int row) {
      const float* rp = &s_seq[phase + row * D_];
      const float f0 = rp[0],  f1 = rp[1],  f2 = rp[2],  f3 = rp[3];
      const float f4 = rp[4],  f5 = rp[5],  f6 = rp[6],  f7 = rp[7];
      const float f8 = rp[8],  f9 = rp[9],  f10 = rp[10], f11 = rp[11];
      const float f12 = rp[12], f13 = rp[13], f14 = rp[14], f15 = rp[15];
      const float f16 = rp[16];
      float sA = ch0, sB = ch1;
      sA = fmaf(qk0[0],  f0,  sA); sB = fmaf(qk1[0],  f0,  sB);
      sA = fmaf(qk0[1],  f1,  sA); sB = fmaf(qk1[1],  f1,  sB);
      sA = fmaf(qk0[2],  f2,  sA); sB = fmaf(qk1[2],  f2,  sB);
      sA = fmaf(qk0[3],  f3,  sA); sB = fmaf(qk1[3],  f3,  sB);
      sA = fmaf(qk0[4],  f4,  sA); sB = fmaf(qk1[4],  f4,  sB);
      sA = fmaf(qk0[5],  f5,  sA); sB = fmaf(qk1[5],  f5,  sB);
      sA = fmaf(qk0[6],  f6,  sA); sB = fmaf(qk1[6],  f6,  sB);
      sA = fmaf(qk0[7],  f7,  sA); sB = fmaf(qk1[7],  f7,  sB);
      sA = fmaf(qk0[8],  f8,  sA); sB = fmaf(qk1[8],  f8,  sB);
      sA = fmaf(qk0[9],  f9,  sA); sB = fmaf(qk1[9],  f9,  sB);
      sA = fmaf(qk0[10], f10, sA); sB = fmaf(qk1[10], f10, sB);
      sA = fmaf(qk0[11], f11, sA); sB = fmaf(qk1[11], f11, sB);
      sA = fmaf(qk0[12], f12, sA); sB = fmaf(qk1[12], f12, sB);
      sA = fmaf(qk0[13], f13, sA); sB = fmaf(qk1[13], f13, sB);
      sA = fmaf(qk0[14], f14, sA); sB = fmaf(qk1[14], f14, sB);
      sA = fmaf(qk0[15], f15, sA); sB = fmaf(qk1[15], f15, sB);
      sA = fmaf(qk0[16], f16, sA); sB = fmaf(qk1[16], f16, sB);
      const bool lv = (row < nrows) && (f0 != 0.f);
      const float p0 = lv ? __expf(sA) : 0.f;
      const float p1 = lv ? __expf(sB) : 0.f;
      den0 += p0; den1 += p1;
      acc0[0]  = fmaf(p0, f0,  acc0[0]);  acc1[0]  = fmaf(p1, f0,  acc1[0]);
      acc0[1]  = fmaf(p0, f1,  acc0[1]);  acc1[1]  = fmaf(p1, f1,  acc1[1]);
      acc0[2]  = fmaf(p0, f2,  acc0[2]);  acc1[2]  = fmaf(p1, f2,  acc1[2]);
      acc0[3]  = fmaf(p0, f3,  acc0[3]);  acc1[3]  = fmaf(p1, f3,  acc1[3]);
      acc0[4]  = fmaf(p0, f4,  acc0[4]);  acc1[4]  = fmaf(p1, f4,  acc1[4]);
      acc0[5]  = fmaf(p0, f5,  acc0[5]);  acc1[5]  = fmaf(p1, f5,  acc1[5]);
      acc0[6]  = fmaf(p0, f6,  acc0[6]);  acc1[6]  = fmaf(p1, f6,  acc1[6]);
      acc0[7]  = fmaf(p0, f7,  acc0[7]);  acc1[7]  = fmaf(p1, f7,  acc1[7]);
      acc0[8]  = fmaf(p0, f8,  acc0[8]);  acc1[8]  = fmaf(p1, f8,  acc1[8]);
      acc0[9]  = fmaf(p0, f9,  acc0[9]);  acc1[9]  = fmaf(p1, f9,  acc1[9]);
      acc0[10] = fmaf(p0, f10, acc0[10]); acc1[10] = fmaf(p1, f10, acc1[10]);
      acc0[11] = fmaf(p0, f11, acc0[11]); acc1[11] = fmaf(p1, f11, acc1[11]);
      acc0[12] = fmaf(p0, f12, acc0[12]); acc1[12] = fmaf(p1, f12, acc1[12]);
      acc0[13] = fmaf(p0, f13, acc0[13]); acc1[13] = fmaf(p1, f13, acc1[13]);
      acc0[14] = fmaf(p0, f14, acc0[14]); acc1[14] = fmaf(p1, f14, acc1[14]);
      acc0[15] = fmaf(p0, f15, acc0[15]); acc1[15] = fmaf(p1, f15, acc1[15]);
      acc0[16] = fmaf(p0, f16, acc0[16]); acc1[16] = fmaf(p1, f16, acc1[16]);
    };

    {
      const int s0r = w * 64;
      if (s0r < nrows) {
        dorow(s0r + rg); dorow(s0r + rg + 16); dorow(s0r + rg + 32); dorow(s0r + rg + 48);
      }
      const int s1r = 256 + w * 64;
      if (s1r < nrows) {
        dorow(s1r + rg); dorow(s1r + rg + 16); dorow(s1r + rg + 32); dorow(s1r + rg + 48);
      }
    }

    #pragma unroll
    for (int m = 1; m <= 8; m <<= 1) {
      den0 += __shfl_xor(den0, m, 64);
      den1 += __shfl_xor(den1, m, 64);
      #pragma unroll
      for (int d = 0; d < D_; ++d) {
        acc0[d] += __shfl_xor(acc0[d], m, 64);
        acc1[d] += __shfl_xor(acc1[d], m, 64);
      }
    }
    if (rg == 0) {
      float* p0p = &s_part[(w * H_ + 2*hp) * 18];
      float* p1p = &s_part[(w * H_ + 2*hp + 1) * 18];
      p0p[0] = den0; p1p[0] = den1;
      #pragma unroll
      for (int d = 0; d < D_; ++d) { p0p[1 + d] = acc0[d]; p1p[1 + d] = acc1[d]; }
    }
    __syncthreads();

    if (t < 136) {
      const int hh = t / D_, d = t - hh * D_;
      float dn = 0.f, ac = 0.f;
      #pragma unroll
      for (int ww = 0; ww < 4; ++ww) {
        const float* pp = &s_part[(ww * H_ + hh) * 18];
        dn += pp[0]; ac += pp[1 + d];
      }
      s_swn[t] = ac / dn;
    }
    __syncthreads();
    if (t < 136) {
      const int hh = t / D_, e = t - hh * D_;
      float s = bv[t];
      #pragma unroll
      for (int d = 0; d < D_; ++d) s = fmaf(Wv[hh*289 + e*D_ + d], s_swn[hh*D_ + d], s);
      s_agg[t] = s;
    }
    __syncthreads();
    if (t < 136) {
      const int o = t >> 3, pt = t & 7;
      float s = 0.f;
      #pragma unroll
      for (int j = 0; j < D_; ++j) s = fmaf(Wo[o*136 + pt*D_ + j], s_agg[pt*D_ + j], s);
      s_wp[t] = s;
    }
    __syncthreads();
    if (t < D_) {
      float s = bo[t];
      #pragma unroll
      for (int pt = 0; pt < 8; ++pt) s += s_wp[t*8 + pt];
      comb[b*26 + t] = s;
    } else if (t < 26) {
      comb[b*26 + t] = x[b * XROW + (t - D_)];
    }
    __syncthreads();
    if (t == 0) {
      __threadfence();                      // publish comb device-wide
      atomicExch(&flags[b], 1);             // device-scope release flag
    }
    return;
  }

  // ======================= MLP role (blocks 2048..2559) =======================
  float* s_red  = smem;                     // [3][4][256] = 3072
  float* s_h2   = smem + 3072;              // [4][256] = 1024
  float* s_comb = smem + 4096;              // [4][28]

  const int mid = bid - B_;
  const int b0 = mid * 4;

  if (t < 4) {
    while (atomicAdd(&flags[b0 + t], 0) == 0) __builtin_amdgcn_s_sleep(16);
  }
  __syncthreads();
  __threadfence();                          // acquire: see producers' comb

  if (t < 104) {
    const int bb = t / 26, k = t - bb * 26;
    s_comb[bb * 28 + k] = comb[(size_t)(b0 + bb) * 26 + k];
  }
  __syncthreads();

  const int kq = t >> 6, ln = t & 63;

  #pragma unroll 1
  for (int p = 0; p < 2; ++p) {
    const float* W1  = p ? vW1  : pW1;   const float* B1 = p ? vb1 : pb1;
    const float* W2t = p ? vW2t : pW2t;  const float* B2 = p ? vb2 : pb2;

    // layer 1: output i = t for 4 batches, in registers
    float h[4];
    {
      float a[4] = {0.f, 0.f, 0.f, 0.f};
      const float* wr = W1 + t * 26;
      for (int k = 0; k < 26; ++k) {
        const float wk = wr[k];
        #pragma unroll
        for (int bb = 0; bb < 4; ++bb) a[bb] = fmaf(wk, s_comb[bb * 28 + k], a[bb]);
      }
      const float bias = B1[t];
      #pragma unroll
      for (int bb = 0; bb < 4; ++bb) h[bb] = fmaxf(a[bb] + bias, 0.f);
    }

    // layer 2: wave kq consumes its own k-slice via readlane
    float4 acc[4];
    #pragma unroll
    for (int bb = 0; bb < 4; ++bb) acc[bb] = make_float4(0.f, 0.f, 0.f, 0.f);
    {
      const float* wbase = W2t + (size_t)(kq * 64) * HID_ + 4 * ln;
      #pragma unroll 8
      for (int jj = 0; jj < 64; ++jj) {
        const float4 wv = *(const float4*)(wbase + (size_t)jj * HID_);
        #pragma unroll
        for (int bb = 0; bb < 4; ++bb) {
          const float hv = bclane(h[bb], jj);
          acc[bb].x = fmaf(wv.x, hv, acc[bb].x);
          acc[bb].y = fmaf(wv.y, hv, acc[bb].y);
          acc[bb].z = fmaf(wv.z, hv, acc[bb].z);
          acc[bb].w = fmaf(wv.w, hv, acc[bb].w);
        }
      }
    }
    if (kq > 0) {
      #pragma unroll
      for (int bb = 0; bb < 4; ++bb)
        *(float4*)&s_red[((kq - 1) * 4 + bb) * HID_ + 4 * ln] = acc[bb];
    }
    __syncthreads();
    if (kq == 0) {
      const float4 bias = *(const float4*)&B2[4 * ln];
      #pragma unroll
      for (int bb = 0; bb < 4; ++bb) {
        const float4 r0 = *(const float4*)&s_red[(0 * 4 + bb) * HID_ + 4 * ln];
        const float4 r1 = *(const float4*)&s_red[(1 * 4 + bb) * HID_ + 4 * ln];
        const float4 r2 = *(const float4*)&s_red[(2 * 4 + bb) * HID_ + 4 * ln];
        float4 rr;
        rr.x = fmaxf(acc[bb].x + r0.x + r1.x + r2.x + bias.x, 0.f);
        rr.y = fmaxf(acc[bb].y + r0.y + r1.y + r2.y + bias.y, 0.f);
        rr.z = fmaxf(acc[bb].z + r0.z + r1.z + r2.z + bias.z, 0.f);
        rr.w = fmaxf(acc[bb].w + r0.w + r1.w + r2.w + bias.w, 0.f);
        *(float4*)&s_h2[bb * HID_ + 4 * ln] = rr;
      }
    }
    __syncthreads();

    if (p == 0) {
      if (t < 92) {                         // policy: 4 batches x 23 outputs
        const int bb = t / OUT_, o = t - bb * OUT_;
        const float4* w4 = (const float4*)(pW3 + o * HID_);
        const float4* h4 = (const float4*)&s_h2[bb * HID_];
        float s = pb3[o];
        for (int k = 0; k < 64; ++k) {
          const float4 wv = w4[k], hv = h4[k];
          s = fmaf(wv.x, hv.x, fmaf(wv.y, hv.y, fmaf(wv.z, hv.z, fmaf(wv.w, hv.w, s))));
        }
        out[(size_t)(b0 + bb) * OUT_ + o] = s;
      }
    } else {
      if (t < 4) {                          // value: 4 batches x 1 output
        const int bb = t;
        const float4* w4 = (const float4*)vW3;
        const float4* h4 = (const float4*)&s_h2[bb * HID_];
        float s = vb3[0];
        for (int k = 0; k < 64; ++k) {
          const float4 wv = w4[k], hv = h4[k];
          s = fmaf(wv.x, hv.x, fmaf(wv.y, hv.y, fmaf(wv.z, hv.z, fmaf(wv.w, hv.w, s))));
        }
        out[(size_t)B_ * OUT_ + b0 + bb] = s;
      }
    }
    __syncthreads();
  }
}

extern "C" void kernel_launch(void* const* d_in, const int* in_sizes, int n_in,
                              void* d_out, int out_size, void* d_ws, size_t ws_size,
                              hipStream_t stream) {
  (void)in_sizes; (void)n_in; (void)out_size; (void)ws_size;
  const float* x   = (const float*)d_in[0];
  const float* Wk  = (const float*)d_in[1];
  const float* bk  = (const float*)d_in[2];
  const float* Wv  = (const float*)d_in[3];
  const float* bv  = (const float*)d_in[4];
  const float* q   = (const float*)d_in[5];
  const float* Wo  = (const float*)d_in[6];
  const float* bo  = (const float*)d_in[7];
  const float* pW1 = (const float*)d_in[8];
  const float* pb1 = (const float*)d_in[9];
  const float* pW2 = (const float*)d_in[10];
  const float* pb2 = (const float*)d_in[11];
  const float* pW3 = (const float*)d_in[12];
  const float* pb3 = (const float*)d_in[13];
  const float* vW1 = (const float*)d_in[14];
  const float* vb1 = (const float*)d_in[15];
  const float* vW2 = (const float*)d_in[16];
  const float* vb2 = (const float*)d_in[17];
  const float* vW3 = (const float*)d_in[18];
  const float* vb3 = (const float*)d_in[19];
  float* out = (float*)d_out;

  // workspace: pW2t (65536) | vW2t (65536) | qkc (160) | comb (2048*26) | flags (2048 int)
  float* pW2t = (float*)d_ws;
  float* vW2t = pW2t + (size_t)HID_ * HID_;
  float* qkc  = vW2t + (size_t)HID_ * HID_;
  float* comb = qkc + 160;
  int*   flags = (int*)(comb + (size_t)B_ * 26);

  prep_kernel<<<129, 256, 0, stream>>>(pW2, vW2, Wk, bk, q, pW2t, vW2t, qkc);
  zeroflags_kernel<<<4, 512, 0, stream>>>(flags);
  fused_pc_kernel<<<B_ + B_ / 4, 256, 0, stream>>>(x, qkc, Wv, bv, Wo, bo,
                                                   pW1, pb1, pW2t, pb2, pW3, pb3,
                                                   vW1, vb1, vW2t, vb2, vW3, vb3,
                                                   comb, flags, out);
}

// Round 21
// 52.559 us; speedup vs baseline: 2.7495x; 2.7495x over previous
//
#include <hip/hip_runtime.h>
#include <hip/hip_bf16.h>

#define B_ 2048
#define D_ 17
#define H_ 8
#define HID_ 256
#define OUT_ 23
#define XROW 8721       /* 513*17 floats per batch */
#define SEQN 8704       /* 512*17 seq floats per batch */
#define LAST4 4465151   /* last valid float4 index of x (2048*8721/4 - 1) */

typedef unsigned int u32;
typedef const __attribute__((address_space(1))) u32* gp1_t;
typedef __attribute__((address_space(3))) u32* lp3_t;

__device__ __forceinline__ float bclane(float v, int l) {  // wave broadcast via readlane
  return __uint_as_float(__builtin_amdgcn_readlane(__float_as_uint(v), l));
}

// fire-and-forget 16B/lane global->LDS (dst = wave-uniform base + lane*16)
__device__ __forceinline__ void gload_lds16(const float4* gsrc_lane, float* lds_wave_base) {
  __builtin_amdgcn_global_load_lds((gp1_t)(const void*)gsrc_lane,
                                   (lp3_t)(void*)lds_wave_base, 16, 0, 0);
}

// ---------------- Kernel 1: prep — transpose W2s + fold q into Wk ----------------
__global__ __launch_bounds__(256) void prep_kernel(
    const float* __restrict__ pW2, const float* __restrict__ vW2,
    const float* __restrict__ Wk, const float* __restrict__ bk,
    const float* __restrict__ q,
    float* __restrict__ pW2t, float* __restrict__ vW2t, float* __restrict__ qkc)
{
  const int bid = blockIdx.x;
  const int t = threadIdx.x;
  if (bid == 128) {
    if (t < H_ * D_) {
      const int h = t / D_, dd = t - h * D_;
      float s = 0.f;
      #pragma unroll
      for (int e = 0; e < D_; ++e) s = fmaf(Wk[h*289 + e*D_ + dd], q[h*D_ + e], s);
      qkc[h*18 + dd] = s;
    } else if (t < H_ * D_ + H_) {
      const int h = t - H_ * D_;
      float s = 0.f;
      #pragma unroll
      for (int e = 0; e < D_; ++e) s = fmaf(bk[h*D_ + e], q[h*D_ + e], s);
      qkc[h*18 + 17] = s;
    }
    return;
  }
  __shared__ float tile[32][33];
  const int m = bid >> 6, tid = bid & 63;
  const int ti = (tid >> 3) * 32, tk = (tid & 7) * 32;
  const float* src = m ? vW2 : pW2;
  float* dst = m ? vW2t : pW2t;
  const int tx = t & 31, ty = t >> 5;
  #pragma unroll
  for (int r = 0; r < 4; ++r) tile[ty + 8*r][tx] = src[(ti + ty + 8*r)*HID_ + tk + tx];
  __syncthreads();
  #pragma unroll
  for (int r = 0; r < 4; ++r) dst[(tk + ty + 8*r)*HID_ + ti + tx] = tile[tx][ty + 8*r];
}

// ---------------- Kernel 2: global_load_lds-staged attention -> comb (B x 26) ----------------
// 1 batch/block, 256 thr = 4 waves. Aligned slab x4[s4 + 256j + t] staged LINEARLY into
// LDS by 9 fire-and-forget global_load_lds instructions (no VGPR dst, no per-thread wait;
// drained once at the barrier). Probe gates rounds 5-8. Compute: lane = (hp = lane>>4
// owns heads {2hp,2hp+1}, rg = lane&15); row r at LDS float offset phase + 17r; 17 scalar
// ds_read_b32/row (stride 17 odd -> conflict-free, 4-way broadcast across hp groups).
__global__ __launch_bounds__(256, 4) void attn_comb_kernel(
    const float* __restrict__ x, const float* __restrict__ qkc,
    const float* __restrict__ Wv, const float* __restrict__ bv,
    const float* __restrict__ Wo, const float* __restrict__ bo,
    float* __restrict__ comb)
{
  __shared__ __align__(16) float s_seq[9216];          // 2304 float4 slots (linear slab)
  __shared__ float s_part[4][H_][18];
  __shared__ float s_swn[136];
  __shared__ float s_agg[136];
  __shared__ float s_wp[136];

  const int t = threadIdx.x;
  const int b = blockIdx.x;
  const int w = t >> 6, lane = t & 63;
  const int hp = lane >> 4;          // head pair: heads 2hp, 2hp+1
  const int rg = lane & 15;          // row slot
  const int seq0 = b * XROW + D_;    // first seq float
  const int s4 = seq0 >> 2;          // first float4 containing seq data
  const int phase = seq0 & 3;
  const float4* __restrict__ x4 = (const float4*)x;

  // ---- probe FIRST (its waitcnt leaves staging loads in flight)
  const float pv = x[seq0 + lane * 136];

  // ---- staging rounds 0-4: fire-and-forget, unconditional
  {
    float* dstb = s_seq + ((t & ~63) << 2);            // wave-uniform base (floats)
    const int g0 = s4 + t;
    gload_lds16(x4 + g0,          dstb);
    gload_lds16(x4 + g0 + 256,    dstb + 1024);
    gload_lds16(x4 + g0 + 512,    dstb + 2048);
    gload_lds16(x4 + g0 + 768,    dstb + 3072);
    gload_lds16(x4 + g0 + 1024,   dstb + 4096);

    const unsigned long long live = __ballot(pv != 0.f) | 1ull;
    const int nr = 8 * (64 - __builtin_clzll(live));
    const int rounds = min(9, (nr * D_ + phase + 1023) >> 10);

    if (rounds > 5) gload_lds16(x4 + g0 + 1280, dstb + 5120);
    if (rounds > 6) gload_lds16(x4 + g0 + 1536, dstb + 6144);
    if (rounds > 7) gload_lds16(x4 + g0 + 1792, dstb + 7168);
    if (rounds > 8) gload_lds16(x4 + min(g0 + 2048, LAST4), dstb + 8192);
  }
  const unsigned long long live2 = __ballot(pv != 0.f) | 1ull;
  const int nrows = 8 * (64 - __builtin_clzll(live2));   // len <= nrows <= len+7

  // qk for this lane's two heads (L2-resident)
  const float* q0 = qkc + (2*hp) * 18;
  float qk0[D_], qk1[D_];
  #pragma unroll
  for (int d = 0; d < D_; ++d) { qk0[d] = q0[d]; qk1[d] = q0[18 + d]; }
  const float ch0 = q0[17], ch1 = q0[35];

  __syncthreads();                   // drains all global_load_lds (vmcnt 0) + barrier

  // ---- compute: pass p, wave segment rows [p*256 + w*64, +64), lane rows rg+16k
  float den0 = 0.f, den1 = 0.f;
  float acc0[D_], acc1[D_];
  #pragma unroll
  for (int d = 0; d < D_; ++d) { acc0[d] = 0.f; acc1[d] = 0.f; }

  auto dorow = [&](int row) {
    const float* rp = &s_seq[phase + row * D_];        // 17 scalar ds_read_b32
    const float f0 = rp[0],  f1 = rp[1],  f2 = rp[2],  f3 = rp[3];
    const float f4 = rp[4],  f5 = rp[5],  f6 = rp[6],  f7 = rp[7];
    const float f8 = rp[8],  f9 = rp[9],  f10 = rp[10], f11 = rp[11];
    const float f12 = rp[12], f13 = rp[13], f14 = rp[14], f15 = rp[15];
    const float f16 = rp[16];
    float sA = ch0, sB = ch1;
    sA = fmaf(qk0[0],  f0,  sA); sB = fmaf(qk1[0],  f0,  sB);
    sA = fmaf(qk0[1],  f1,  sA); sB = fmaf(qk1[1],  f1,  sB);
    sA = fmaf(qk0[2],  f2,  sA); sB = fmaf(qk1[2],  f2,  sB);
    sA = fmaf(qk0[3],  f3,  sA); sB = fmaf(qk1[3],  f3,  sB);
    sA = fmaf(qk0[4],  f4,  sA); sB = fmaf(qk1[4],  f4,  sB);
    sA = fmaf(qk0[5],  f5,  sA); sB = fmaf(qk1[5],  f5,  sB);
    sA = fmaf(qk0[6],  f6,  sA); sB = fmaf(qk1[6],  f6,  sB);
    sA = fmaf(qk0[7],  f7,  sA); sB = fmaf(qk1[7],  f7,  sB);
    sA = fmaf(qk0[8],  f8,  sA); sB = fmaf(qk1[8],  f8,  sB);
    sA = fmaf(qk0[9],  f9,  sA); sB = fmaf(qk1[9],  f9,  sB);
    sA = fmaf(qk0[10], f10, sA); sB = fmaf(qk1[10], f10, sB);
    sA = fmaf(qk0[11], f11, sA); sB = fmaf(qk1[11], f11, sB);
    sA = fmaf(qk0[12], f12, sA); sB = fmaf(qk1[12], f12, sB);
    sA = fmaf(qk0[13], f13, sA); sB = fmaf(qk1[13], f13, sB);
    sA = fmaf(qk0[14], f14, sA); sB = fmaf(qk1[14], f14, sB);
    sA = fmaf(qk0[15], f15, sA); sB = fmaf(qk1[15], f15, sB);
    sA = fmaf(qk0[16], f16, sA); sB = fmaf(qk1[16], f16, sB);
    const bool lv = (row < nrows) && (f0 != 0.f);      // masked rows exact zeros
    const float p0 = lv ? __expf(sA) : 0.f;
    const float p1 = lv ? __expf(sB) : 0.f;
    den0 += p0; den1 += p1;
    acc0[0]  = fmaf(p0, f0,  acc0[0]);  acc1[0]  = fmaf(p1, f0,  acc1[0]);
    acc0[1]  = fmaf(p0, f1,  acc0[1]);  acc1[1]  = fmaf(p1, f1,  acc1[1]);
    acc0[2]  = fmaf(p0, f2,  acc0[2]);  acc1[2]  = fmaf(p1, f2,  acc1[2]);
    acc0[3]  = fmaf(p0, f3,  acc0[3]);  acc1[3]  = fmaf(p1, f3,  acc1[3]);
    acc0[4]  = fmaf(p0, f4,  acc0[4]);  acc1[4]  = fmaf(p1, f4,  acc1[4]);
    acc0[5]  = fmaf(p0, f5,  acc0[5]);  acc1[5]  = fmaf(p1, f5,  acc1[5]);
    acc0[6]  = fmaf(p0, f6,  acc0[6]);  acc1[6]  = fmaf(p1, f6,  acc1[6]);
    acc0[7]  = fmaf(p0, f7,  acc0[7]);  acc1[7]  = fmaf(p1, f7,  acc1[7]);
    acc0[8]  = fmaf(p0, f8,  acc0[8]);  acc1[8]  = fmaf(p1, f8,  acc1[8]);
    acc0[9]  = fmaf(p0, f9,  acc0[9]);  acc1[9]  = fmaf(p1, f9,  acc1[9]);
    acc0[10] = fmaf(p0, f10, acc0[10]); acc1[10] = fmaf(p1, f10, acc1[10]);
    acc0[11] = fmaf(p0, f11, acc0[11]); acc1[11] = fmaf(p1, f11, acc1[11]);
    acc0[12] = fmaf(p0, f12, acc0[12]); acc1[12] = fmaf(p1, f12, acc1[12]);
    acc0[13] = fmaf(p0, f13, acc0[13]); acc1[13] = fmaf(p1, f13, acc1[13]);
    acc0[14] = fmaf(p0, f14, acc0[14]); acc1[14] = fmaf(p1, f14, acc1[14]);
    acc0[15] = fmaf(p0, f15, acc0[15]); acc1[15] = fmaf(p1, f15, acc1[15]);
    acc0[16] = fmaf(p0, f16, acc0[16]); acc1[16] = fmaf(p1, f16, acc1[16]);
  };

  {
    const int s0r = w * 64;            // pass 0: rows 0..255
    if (s0r < nrows) {
      dorow(s0r + rg);
      dorow(s0r + rg + 16);
      dorow(s0r + rg + 32);
      dorow(s0r + rg + 48);
    }
    const int s1r = 256 + w * 64;      // pass 1: rows 256..511
    if (s1r < nrows) {
      dorow(s1r + rg);
      dorow(s1r + rg + 16);
      dorow(s1r + rg + 32);
      dorow(s1r + rg + 48);
    }
  }

  // ---- reduce over the 16 rg lanes of each hp group
  #pragma unroll
  for (int m = 1; m <= 8; m <<= 1) {
    den0 += __shfl_xor(den0, m, 64);
    den1 += __shfl_xor(den1, m, 64);
    #pragma unroll
    for (int d = 0; d < D_; ++d) {
      acc0[d] += __shfl_xor(acc0[d], m, 64);
      acc1[d] += __shfl_xor(acc1[d], m, 64);
    }
  }
  if (rg == 0) {
    float* p0p = &s_part[w][2*hp][0];
    float* p1p = &s_part[w][2*hp + 1][0];
    p0p[0] = den0; p1p[0] = den1;
    #pragma unroll
    for (int d = 0; d < D_; ++d) { p0p[1 + d] = acc0[d]; p1p[1 + d] = acc1[d]; }
  }
  __syncthreads();

  // ---- finish (verified phases)
  if (t < 136) {                        // swn = (sum 4 wave-parts acc) / (sum den)
    const int hh = t / D_, d = t - hh * D_;
    float dn = 0.f, ac = 0.f;
    #pragma unroll
    for (int ww = 0; ww < 4; ++ww) { dn += s_part[ww][hh][0]; ac += s_part[ww][hh][1 + d]; }
    s_swn[t] = ac / dn;
  }
  __syncthreads();
  if (t < 136) {                        // agg = bv + Wv·swn
    const int hh = t / D_, e = t - hh * D_;
    float s = bv[t];
    #pragma unroll
    for (int d = 0; d < D_; ++d) s = fmaf(Wv[hh*289 + e*D_ + d], s_swn[hh*D_ + d], s);
    s_agg[t] = s;
  }
  __syncthreads();
  if (t < 136) {                        // Wo partials: 17 outs x 8 k-parts
    const int o = t >> 3, pt = t & 7;
    float s = 0.f;
    #pragma unroll
    for (int j = 0; j < D_; ++j) s = fmaf(Wo[o*136 + pt*D_ + j], s_agg[pt*D_ + j], s);
    s_wp[t] = s;
  }
  __syncthreads();
  if (t < D_) {
    float s = bo[t];
    #pragma unroll
    for (int pt = 0; pt < 8; ++pt) s += s_wp[t*8 + pt];
    comb[b*26 + t] = s;
  } else if (t < 26) {
    comb[b*26 + t] = x[b * XROW + (t - D_)];   // special = x[b, 0, 0..8]
  }
}

// ---------------- Kernel 3: fused policy+value MLPs (readlane layer 2) ----------------
__global__ __launch_bounds__(512) void mlp_kernel(
    const float* __restrict__ comb,
    const float* __restrict__ pW1, const float* __restrict__ pb1,
    const float* __restrict__ pW2t, const float* __restrict__ pb2,
    const float* __restrict__ pW3, const float* __restrict__ pb3,
    const float* __restrict__ vW1, const float* __restrict__ vb1,
    const float* __restrict__ vW2t, const float* __restrict__ vb2,
    const float* __restrict__ vW3, const float* __restrict__ vb3,
    float* __restrict__ out)
{
  __shared__ float s_comb[8][26];
  __shared__ __align__(16) float s_red[2][3][8][HID_];
  __shared__ __align__(16) float s_h2[2][8][HID_];

  const int t = threadIdx.x;
  const int b0 = blockIdx.x * 8;
  const int p = t >> 8;
  const int kq = (t >> 6) & 3;
  const int ln = t & 63;

  if (t < 208) { const int bb = t / 26, k = t - bb*26; s_comb[bb][k] = comb[(size_t)(b0 + bb)*26 + k]; }
  __syncthreads();

  const float* W1  = p ? vW1  : pW1;   const float* B1 = p ? vb1 : pb1;
  const float* W2t = p ? vW2t : pW2t;  const float* B2 = p ? vb2 : pb2;

  // layer 1: output i = kq*64+ln for 8 batches, kept in registers
  float h[8];
  {
    const int i = kq * 64 + ln;
    float a[8];
    #pragma unroll
    for (int bb = 0; bb < 8; ++bb) a[bb] = 0.f;
    const float* wr = W1 + i * 26;
    for (int k = 0; k < 26; ++k) {
      const float wk = wr[k];
      #pragma unroll
      for (int bb = 0; bb < 8; ++bb) a[bb] = fmaf(wk, s_comb[bb][k], a[bb]);
    }
    const float bias = B1[i];
    #pragma unroll
    for (int bb = 0; bb < 8; ++bb) h[bb] = fmaxf(a[bb] + bias, 0.f);
  }

  // layer 2: k-slice [kq*64, +64); h1[bb][kq*64+jj] lives in lane jj of THIS wave
  float4 acc[8];
  #pragma unroll
  for (int bb = 0; bb < 8; ++bb) acc[bb] = make_float4(0.f, 0.f, 0.f, 0.f);
  {
    const float* wbase = W2t + (size_t)(kq * 64) * HID_ + 4 * ln;
    #pragma unroll 8
    for (int jj = 0; jj < 64; ++jj) {
      const float4 wv = *(const float4*)(wbase + (size_t)jj * HID_);
      #pragma unroll
      for (int bb = 0; bb < 8; ++bb) {
        const float hv = bclane(h[bb], jj);
        acc[bb].x = fmaf(wv.x, hv, acc[bb].x);
        acc[bb].y = fmaf(wv.y, hv, acc[bb].y);
        acc[bb].z = fmaf(wv.z, hv, acc[bb].z);
        acc[bb].w = fmaf(wv.w, hv, acc[bb].w);
      }
    }
  }
  if (kq > 0) {
    #pragma unroll
    for (int bb = 0; bb < 8; ++bb) *(float4*)&s_red[p][kq - 1][bb][4 * ln] = acc[bb];
  }
  __syncthreads();
  if (kq == 0) {
    const float4 bias = *(const float4*)&B2[4 * ln];
    #pragma unroll
    for (int bb = 0; bb < 8; ++bb) {
      const float4 r0 = *(const float4*)&s_red[p][0][bb][4 * ln];
      const float4 r1 = *(const float4*)&s_red[p][1][bb][4 * ln];
      const float4 r2 = *(const float4*)&s_red[p][2][bb][4 * ln];
      float4 rr;
      rr.x = fmaxf(acc[bb].x + r0.x + r1.x + r2.x + bias.x, 0.f);
      rr.y = fmaxf(acc[bb].y + r0.y + r1.y + r2.y + bias.y, 0.f);
      rr.z = fmaxf(acc[bb].z + r0.z + r1.z + r2.z + bias.z, 0.f);
      rr.w = fmaxf(acc[bb].w + r0.w + r1.w + r2.w + bias.w, 0.f);
      *(float4*)&s_h2[p][bb][4 * ln] = rr;
    }
  }
  __syncthreads();

  // layer 3
  if (t < 184) {                        // policy: 8 batches x 23 outputs
    const int bb = t / OUT_, o = t - bb * OUT_;
    const float4* w4 = (const float4*)(pW3 + o * HID_);
    const float4* h4 = (const float4*)&s_h2[0][bb][0];
    float s = pb3[o];
    for (int k = 0; k < 64; ++k) {
      const float4 wv = w4[k], hv = h4[k];
      s = fmaf(wv.x, hv.x, fmaf(wv.y, hv.y, fmaf(wv.z, hv.z, fmaf(wv.w, hv.w, s))));
    }
    out[(size_t)(b0 + bb) * OUT_ + o] = s;
  } else if (t >= 256 && t < 264) {     // value: 8 batches x 1 output
    const int bb = t - 256;
    const float4* w4 = (const float4*)vW3;
    const float4* h4 = (const float4*)&s_h2[1][bb][0];
    float s = vb3[0];
    for (int k = 0; k < 64; ++k) {
      const float4 wv = w4[k], hv = h4[k];
      s = fmaf(wv.x, hv.x, fmaf(wv.y, hv.y, fmaf(wv.z, hv.z, fmaf(wv.w, hv.w, s))));
    }
    out[(size_t)B_ * OUT_ + b0 + bb] = s;
  }
}

extern "C" void kernel_launch(void* const* d_in, const int* in_sizes, int n_in,
                              void* d_out, int out_size, void* d_ws, size_t ws_size,
                              hipStream_t stream) {
  (void)in_sizes; (void)n_in; (void)out_size; (void)ws_size;
  const float* x   = (const float*)d_in[0];
  const float* Wk  = (const float*)d_in[1];
  const float* bk  = (const float*)d_in[2];
  const float* Wv  = (const float*)d_in[3];
  const float* bv  = (const float*)d_in[4];
  const float* q   = (const float*)d_in[5];
  const float* Wo  = (const float*)d_in[6];
  const float* bo  = (const float*)d_in[7];
  const float* pW1 = (const float*)d_in[8];
  const float* pb1 = (const float*)d_in[9];
  const float* pW2 = (const float*)d_in[10];
  const float* pb2 = (const float*)d_in[11];
  const float* pW3 = (const float*)d_in[12];
  const float* pb3 = (const float*)d_in[13];
  const float* vW1 = (const float*)d_in[14];
  const float* vb1 = (const float*)d_in[15];
  const float* vW2 = (const float*)d_in[16];
  const float* vb2 = (const float*)d_in[17];
  const float* vW3 = (const float*)d_in[18];
  const float* vb3 = (const float*)d_in[19];
  float* out = (float*)d_out;

  // workspace: pW2t (65536) | vW2t (65536) | qkc (160) | comb (2048*26) floats
  float* pW2t = (float*)d_ws;
  float* vW2t = pW2t + (size_t)HID_ * HID_;
  float* qkc  = vW2t + (size_t)HID_ * HID_;
  float* comb = qkc + 160;

  prep_kernel<<<129, 256, 0, stream>>>(pW2, vW2, Wk, bk, q, pW2t, vW2t, qkc);
  attn_comb_kernel<<<B_, 256, 0, stream>>>(x, qkc, Wv, bv, Wo, bo, comb);
  mlp_kernel<<<B_ / 8, 512, 0, stream>>>(comb, pW1, pb1, pW2t, pb2, pW3, pb3,
                                         vW1, vb1, vW2t, vb2, vW3, vb3, out);
}